// Round 1
// baseline (1130.806 us; speedup 1.0000x reference)
//
#include <hip/hip_runtime.h>

// MLPP: 8x 256x256 GEMMs over gathered views of x[4,32,32,32,256] (fp32 in/out).
// Pipeline: pack -> att -> hwc(c,h,w phased RMW) -> comb(+W1,+x) -> d -> fin(W2,res,W3+I,res)
// d_out doubles as x1 scratch between comb and fin.

typedef __attribute__((ext_vector_type(8))) short bf16x8;
typedef __attribute__((ext_vector_type(4))) float f32x4;
typedef __attribute__((ext_vector_type(4))) unsigned short u16x4;
typedef unsigned short u16;
typedef unsigned int u32;

#define DEV __device__ __forceinline__

DEV u16 f2b(float f) {  // fp32 -> bf16 RNE
  union { float f; u32 u; } v; v.f = f;
  u32 r = v.u + 0x7FFFu + ((v.u >> 16) & 1u);
  return (u16)(r >> 16);
}
DEV float b2f(u16 b) {
  union { u32 u; float f; } v; v.u = ((u32)b) << 16; return v.f;
}

// All LDS tiles: [256 rows][256 bf16] = 128 KiB, row pitch 512B,
// XOR swizzle spreads the 32 16B-slots of a row across banks.
DEV int lds_off(int row, int colByte) {
  return (row << 9) + (colByte ^ ((row & 31) << 4));
}
DEV bf16x8 ld_lds(const u16* lds, int row, int colByte) {
  return *(const bf16x8*)((const char*)lds + lds_off(row, colByte));
}
DEV bf16x8 ld_glb(const u16* g, int row, int kByte) {  // row-major [256][256] bf16
  return *(const bf16x8*)((const char*)g + (row << 9) + kByte);
}

DEV void zero_acc(f32x4 acc[8][4]) {
#pragma unroll
  for (int i = 0; i < 8; ++i)
#pragma unroll
    for (int j = 0; j < 4; ++j) {
      acc[i][j][0] = 0.f; acc[i][j][1] = 0.f; acc[i][j][2] = 0.f; acc[i][j][3] = 0.f;
    }
}

// D[m][n] = sum_k P[m][k] * Q[n][k], M=N=K=256.
// 8 waves: wave=(wm,wn); wm in {0,1} covers 128 m-rows (8 tiles), wn in {0..3} covers 64 n (4 tiles).
// A-frag: row = tile*16 + (lane&15), k = kk*32 + (lane>>4)*8 + j  (8 contiguous bf16 = 16B)
template <typename LA, typename LB>
DEV void gemm256(LA loadA, LB loadB, f32x4 acc[8][4]) {
#pragma unroll
  for (int kk = 0; kk < 8; ++kk) {
    bf16x8 a[8], b[4];
#pragma unroll
    for (int i = 0; i < 8; ++i) a[i] = loadA(i, kk);
#pragma unroll
    for (int j = 0; j < 4; ++j) b[j] = loadB(j, kk);
#pragma unroll
    for (int i = 0; i < 8; ++i)
#pragma unroll
      for (int j = 0; j < 4; ++j)
        acc[i][j] = __builtin_amdgcn_mfma_f32_16x16x32_bf16(a[i], b[j], acc[i][j], 0, 0, 0);
  }
}

#define WAVE_SETUP                  \
  const int tid = threadIdx.x;      \
  const int lane = tid & 63;        \
  const int wave = tid >> 6;        \
  const int wm = wave >> 2;         \
  const int wn = wave & 3;          \
  const int lr = lane & 15;         \
  const int lk = lane >> 4;

// ---------- weight pack: WT[n*256+k] = W[k*256+n] (+I on diag if addI) ----------
__global__ void k_pack(const float* __restrict__ W, u16* __restrict__ WT, int addI) {
  int n = blockIdx.x;
  int k0 = threadIdx.x * 4;
#pragma unroll
  for (int i = 0; i < 4; ++i) {
    int k = k0 + i;
    float v = W[k * 256 + n];
    if (addI && k == n) v += 1.0f;
    WT[n * 256 + k] = f2b(v);
  }
}

// ---------- attention-block GEMM: D[p][c] = sum_q W_attn[q][p] X[q][c] (+b_attn[p]) ----------
__global__ __launch_bounds__(512, 2) void k_att(const float* __restrict__ x,
    const u16* __restrict__ WTattn, const float* __restrict__ b_attn,
    u16* __restrict__ S_att) {
  __shared__ alignas(16) u16 XT[65536];  // [c][q]
  WAVE_SETUP;
  const int t = blockIdx.x;
  const int d = t & 31, w1 = (t >> 5) & 1, h1 = (t >> 6) & 1, b = t >> 7;
  const int B0 = (((b * 32 + h1 * 16) * 32 + w1 * 16) * 32 + d) * 256;

  // transpose-stage: read x[q][c] coalesced, write XT[c][q]
  for (int i = tid; i < 16384; i += 512) {
    int q = i >> 6;
    int c4 = (i & 63) << 2;
    const float4 v = *(const float4*)(x + B0 + (q >> 4) * 262144 + (q & 15) * 8192 + c4);
    XT[lds_off(c4 + 0, q * 2) >> 1] = f2b(v.x);
    XT[lds_off(c4 + 1, q * 2) >> 1] = f2b(v.y);
    XT[lds_off(c4 + 2, q * 2) >> 1] = f2b(v.z);
    XT[lds_off(c4 + 3, q * 2) >> 1] = f2b(v.w);
  }
  __syncthreads();

  f32x4 acc[8][4];
  zero_acc(acc);
  gemm256(
      [&](int i, int kk) { return ld_glb(WTattn, wm * 128 + i * 16 + lr, kk * 64 + lk * 16); },
      [&](int j, int kk) { return ld_lds(XT, wn * 64 + j * 16 + lr, kk * 64 + lk * 16); },
      acc);

  u16* out = S_att + t * 65536;  // [p][c]
#pragma unroll
  for (int i = 0; i < 8; ++i)
#pragma unroll
    for (int j = 0; j < 4; ++j)
#pragma unroll
      for (int r = 0; r < 4; ++r) {
        int p = wm * 128 + i * 16 + lk * 4 + r;
        int c = wn * 64 + j * 16 + lr;
        out[p * 256 + c] = f2b(acc[i][j][r] + b_attn[p]);
      }
}

// ---------- c + h + w GEMMs, phased RMW into bf16 scratch [pos][c] ----------
__global__ __launch_bounds__(512, 2) void k_hwc(const float* __restrict__ x,
    const u16* __restrict__ WTh, const u16* __restrict__ WTw, const u16* __restrict__ WTc,
    u16* __restrict__ hwc) {
  __shared__ alignas(16) u16 XS[65536];  // [pos][c]
  WAVE_SETUP;
  const int t = blockIdx.x;
  const int d = t & 31, w1 = (t >> 5) & 1, h1 = (t >> 6) & 1, b = t >> 7;
  const int B0 = (((b * 32 + h1 * 16) * 32 + w1 * 16) * 32 + d) * 256;

  for (int i = tid; i < 16384; i += 512) {
    int pos = i >> 6;
    int c4 = (i & 63) << 2;
    const float4 v = *(const float4*)(x + B0 + (pos >> 4) * 262144 + (pos & 15) * 8192 + c4);
    u16x4 pk;
    pk[0] = f2b(v.x); pk[1] = f2b(v.y); pk[2] = f2b(v.z); pk[3] = f2b(v.w);
    *(u16x4*)((char*)XS + lds_off(pos, c4 * 2)) = pk;
  }
  __syncthreads();

  u16* out = hwc + t * 65536;
  f32x4 acc[8][4];

  // phase C: D[pos][c'] = sum_c X[pos][c] Wc[c][c']  (write, no read)
  zero_acc(acc);
  gemm256(
      [&](int i, int kk) { return ld_lds(XS, wm * 128 + i * 16 + lr, kk * 64 + lk * 16); },
      [&](int j, int kk) { return ld_glb(WTc, wn * 64 + j * 16 + lr, kk * 64 + lk * 16); },
      acc);
#pragma unroll
  for (int i = 0; i < 8; ++i)
#pragma unroll
    for (int j = 0; j < 4; ++j)
#pragma unroll
      for (int r = 0; r < 4; ++r) {
        int m = wm * 128 + i * 16 + lk * 4 + r;
        int n = wn * 64 + j * 16 + lr;
        out[m * 256 + n] = f2b(acc[i][j][r]);
      }
  __threadfence();
  __syncthreads();

  // phase H: m=(lc,lw) k=(lh',g'): A[m][k] = XS[khi*16+lw][lc*16+klo]
  zero_acc(acc);
  gemm256(
      [&](int i, int kk) {
        int k = kk * 32 + lk * 8;
        int khi = k >> 4, kloB = (k & 15) * 2;
        int mt = wm * 8 + i;
        return *(const bf16x8*)((const char*)XS + lds_off(khi * 16 + lr, mt * 32 + kloB));
      },
      [&](int j, int kk) { return ld_glb(WTh, wn * 64 + j * 16 + lr, kk * 64 + lk * 16); },
      acc);
#pragma unroll
  for (int i = 0; i < 8; ++i)
#pragma unroll
    for (int j = 0; j < 4; ++j)
#pragma unroll
      for (int r = 0; r < 4; ++r) {
        int m = wm * 128 + i * 16 + lk * 4 + r;   // (lc,lw): lc=m>>4, lw=m&15
        int n = wn * 64 + j * 16 + lr;            // (lh,g):  lh=n>>4, g=n&15
        int pos = ((n >> 4) << 4) + (m & 15);
        int c = ((m >> 4) << 4) + (n & 15);
        u16* p = out + pos * 256 + c;
        *p = f2b(b2f(*p) + acc[i][j][r]);
      }
  __threadfence();
  __syncthreads();

  // phase W: m=(lc,lh) k=(lw',g'): A[m][k] = XS[lh*16+khi][lc*16+klo]
  zero_acc(acc);
  gemm256(
      [&](int i, int kk) {
        int k = kk * 32 + lk * 8;
        int khi = k >> 4, kloB = (k & 15) * 2;
        int mt = wm * 8 + i;
        return *(const bf16x8*)((const char*)XS + lds_off(lr * 16 + khi, mt * 32 + kloB));
      },
      [&](int j, int kk) { return ld_glb(WTw, wn * 64 + j * 16 + lr, kk * 64 + lk * 16); },
      acc);
#pragma unroll
  for (int i = 0; i < 8; ++i)
#pragma unroll
    for (int j = 0; j < 4; ++j)
#pragma unroll
      for (int r = 0; r < 4; ++r) {
        int m = wm * 128 + i * 16 + lk * 4 + r;   // (lc,lh)
        int n = wn * 64 + j * 16 + lr;            // (lw,g)
        int pos = ((m & 15) << 4) + (n >> 4);
        int c = ((m >> 4) << 4) + (n & 15);
        u16* p = out + pos * 256 + c;
        *p = f2b(b2f(*p) + acc[i][j][r]);
      }
}

// ---------- combine + W1 + residual -> x1 (written into d_out) ----------
__global__ __launch_bounds__(512, 2) void k_comb(const float* __restrict__ x,
    const u16* __restrict__ S_att, const u16* __restrict__ hwc,
    const float* __restrict__ bh, const float* __restrict__ bw, const float* __restrict__ bc,
    const u16* __restrict__ WT1, const float* __restrict__ b1,
    float* __restrict__ x1) {
  __shared__ alignas(16) u16 OUT[65536];  // [pos][c]
  WAVE_SETUP;
  const int t = blockIdx.x;
  const int d = t & 31, w1 = (t >> 5) & 1, h1 = (t >> 6) & 1, b = t >> 7;
  const int B0 = (((b * 32 + h1 * 16) * 32 + w1 * 16) * 32 + d) * 256;
  const u16* att_t = S_att + t * 65536;
  const u16* hwc_t = hwc + t * 65536;

  for (int i = tid; i < 16384; i += 512) {
    int pos = i >> 6;
    int c4 = (i & 63) << 2;
    u16x4 av = *(const u16x4*)(att_t + pos * 256 + c4);
    u16x4 hv = *(const u16x4*)(hwc_t + pos * 256 + c4);
    int lh = pos >> 4, lw = pos & 15;
    u16x4 o;
#pragma unroll
    for (int j = 0; j < 4; ++j) {
      int c = c4 + j;
      float attv = b2f(av[j]);  // b_attn already folded in
      float hwv = b2f(hv[j]) + bh[lh * 16 + (c & 15)] + bw[lw * 16 + (c & 15)] + bc[c];
      o[j] = f2b((1.0f + attv) * hwv);
    }
    *(u16x4*)((char*)OUT + lds_off(pos, c4 * 2)) = o;
  }
  __syncthreads();

  f32x4 acc[8][4];
  zero_acc(acc);
  gemm256(
      [&](int i, int kk) { return ld_lds(OUT, wm * 128 + i * 16 + lr, kk * 64 + lk * 16); },
      [&](int j, int kk) { return ld_glb(WT1, wn * 64 + j * 16 + lr, kk * 64 + lk * 16); },
      acc);
#pragma unroll
  for (int i = 0; i < 8; ++i)
#pragma unroll
    for (int j = 0; j < 4; ++j)
#pragma unroll
      for (int r = 0; r < 4; ++r) {
        int m = wm * 128 + i * 16 + lk * 4 + r;
        int n = wn * 64 + j * 16 + lr;
        int g = B0 + (m >> 4) * 262144 + (m & 15) * 8192 + n;
        x1[g] = x[g] + acc[i][j][r] + b1[n];
      }
}

// ---------- d-block gather GEMM ----------
__global__ __launch_bounds__(512, 2) void k_d(const float* __restrict__ x1,
    const u16* __restrict__ WTd, const float* __restrict__ bd, u16* __restrict__ xd) {
  __shared__ alignas(16) u16 XS[65536];  // rows R = wlo*16+ld, cols c
  WAVE_SETUP;
  const int t = blockIdx.x;
  const int d1 = t & 1, wb = (t >> 1) & 1, h = (t >> 2) & 31, b = t >> 7;
  const int B0 = (((b * 32 + h) * 32 + wb * 16) * 32 + d1 * 16) * 256;

  for (int i = tid; i < 16384; i += 512) {
    int R = i >> 6;
    int c4 = (i & 63) << 2;
    const float4 v = *(const float4*)(x1 + B0 + (R >> 4) * 8192 + (R & 15) * 256 + c4);
    u16x4 pk;
    pk[0] = f2b(v.x); pk[1] = f2b(v.y); pk[2] = f2b(v.z); pk[3] = f2b(v.w);
    *(u16x4*)((char*)XS + lds_off(R, c4 * 2)) = pk;
  }
  __syncthreads();

  f32x4 acc[8][4];
  zero_acc(acc);
  // m=(wlo,lc) k=(ld',g'): A[m][k] = XS[wlo*16+khi][lc*16+klo]
  gemm256(
      [&](int i, int kk) {
        int k = kk * 32 + lk * 8;
        int khi = k >> 4, kloB = (k & 15) * 2;
        int mt = wm * 8 + i;
        return *(const bf16x8*)((const char*)XS + lds_off(mt * 16 + khi, lr * 32 + kloB));
      },
      [&](int j, int kk) { return ld_glb(WTd, wn * 64 + j * 16 + lr, kk * 64 + lk * 16); },
      acc);
#pragma unroll
  for (int i = 0; i < 8; ++i)
#pragma unroll
    for (int j = 0; j < 4; ++j)
#pragma unroll
      for (int r = 0; r < 4; ++r) {
        int m = wm * 128 + i * 16 + lk * 4 + r;  // (wlo,lc)
        int n = wn * 64 + j * 16 + lr;           // (ld,g)
        int wlo = m >> 4, lc = m & 15, ld = n >> 4, g = n & 15;
        xd[B0 + wlo * 8192 + ld * 256 + lc * 16 + g] = f2b(acc[i][j][r] + bd[n]);
      }
}

// ---------- W2 + residual, then (W3+I) + b3 -> final ----------
__global__ __launch_bounds__(512, 2) void k_fin(const float* x1,
    const u16* __restrict__ xd, const u16* __restrict__ WT2, const u16* __restrict__ WT3p,
    const float* __restrict__ b2, const float* __restrict__ b3, float* outp) {
  __shared__ alignas(16) u16 X2[65536];
  WAVE_SETUP;
  const int vt = blockIdx.x;
  const int base = vt * 65536;
  const u16* xd_t = xd + base;

  f32x4 acc[8][4];
  zero_acc(acc);
  gemm256(
      [&](int i, int kk) { return ld_glb(xd_t, wm * 128 + i * 16 + lr, kk * 64 + lk * 16); },
      [&](int j, int kk) { return ld_glb(WT2, wn * 64 + j * 16 + lr, kk * 64 + lk * 16); },
      acc);
#pragma unroll
  for (int i = 0; i < 8; ++i)
#pragma unroll
    for (int j = 0; j < 4; ++j)
#pragma unroll
      for (int r = 0; r < 4; ++r) {
        int m = wm * 128 + i * 16 + lk * 4 + r;
        int n = wn * 64 + j * 16 + lr;
        float v = x1[base + m * 256 + n] + acc[i][j][r] + b2[n];
        X2[lds_off(m, n * 2) >> 1] = f2b(v);
      }
  __syncthreads();

  zero_acc(acc);
  gemm256(
      [&](int i, int kk) { return ld_lds(X2, wm * 128 + i * 16 + lr, kk * 64 + lk * 16); },
      [&](int j, int kk) { return ld_glb(WT3p, wn * 64 + j * 16 + lr, kk * 64 + lk * 16); },
      acc);
#pragma unroll
  for (int i = 0; i < 8; ++i)
#pragma unroll
    for (int j = 0; j < 4; ++j)
#pragma unroll
      for (int r = 0; r < 4; ++r) {
        int m = wm * 128 + i * 16 + lk * 4 + r;
        int n = wn * 64 + j * 16 + lr;
        outp[base + m * 256 + n] = acc[i][j][r] + b3[n];
      }
}

extern "C" void kernel_launch(void* const* d_in, const int* in_sizes, int n_in,
                              void* d_out, int out_size, void* d_ws, size_t ws_size,
                              hipStream_t stream) {
  (void)in_sizes; (void)n_in; (void)out_size; (void)ws_size;
  const float* x      = (const float*)d_in[0];
  const float* W_h    = (const float*)d_in[1];
  const float* b_h    = (const float*)d_in[2];
  const float* W_w    = (const float*)d_in[3];
  const float* b_w    = (const float*)d_in[4];
  const float* W_c    = (const float*)d_in[5];
  const float* b_c    = (const float*)d_in[6];
  const float* W_d    = (const float*)d_in[7];
  const float* b_d    = (const float*)d_in[8];
  const float* W_attn = (const float*)d_in[9];
  const float* b_attn = (const float*)d_in[10];
  const float* W_1    = (const float*)d_in[11];
  const float* b_1    = (const float*)d_in[12];
  const float* W_2    = (const float*)d_in[13];
  const float* b_2    = (const float*)d_in[14];
  const float* W_3    = (const float*)d_in[15];
  const float* b_3    = (const float*)d_in[16];
  float* outp = (float*)d_out;

  u16* WT    = (u16*)d_ws;          // 8 * 65536 bf16 (1 MiB)
  u16* S_att = WT + 8 * 65536;      // 33.5M bf16 (64 MiB)
  u16* hwc   = S_att + 33554432;    // 33.5M bf16 (64 MiB)
  u16* xd    = S_att;               // overlay: S_att dead after k_comb

  k_pack<<<256, 64, 0, stream>>>(W_h,    WT + 0 * 65536, 0);
  k_pack<<<256, 64, 0, stream>>>(W_w,    WT + 1 * 65536, 0);
  k_pack<<<256, 64, 0, stream>>>(W_c,    WT + 2 * 65536, 0);
  k_pack<<<256, 64, 0, stream>>>(W_attn, WT + 3 * 65536, 0);
  k_pack<<<256, 64, 0, stream>>>(W_1,    WT + 4 * 65536, 0);
  k_pack<<<256, 64, 0, stream>>>(W_d,    WT + 5 * 65536, 0);
  k_pack<<<256, 64, 0, stream>>>(W_2,    WT + 6 * 65536, 0);
  k_pack<<<256, 64, 0, stream>>>(W_3,    WT + 7 * 65536, 1);  // fold +I

  k_att <<<512, 512, 0, stream>>>(x, WT + 3 * 65536, b_attn, S_att);
  k_hwc <<<512, 512, 0, stream>>>(x, WT + 0 * 65536, WT + 1 * 65536, WT + 2 * 65536, hwc);
  k_comb<<<512, 512, 0, stream>>>(x, S_att, hwc, b_h, b_w, b_c, WT + 4 * 65536, b_1, outp);
  k_d   <<<512, 512, 0, stream>>>(outp, WT + 5 * 65536, b_d, xd);
  k_fin <<<512, 512, 0, stream>>>(outp, xd, WT + 6 * 65536, WT + 7 * 65536, b_2, b_3, outp);
}

// Round 2
// 739.042 us; speedup vs baseline: 1.5301x; 1.5301x over previous
//
#include <hip/hip_runtime.h>

// MLPP: 8x 256x256 GEMMs over gathered views of x[4,32,32,32,256] (fp32 in/out).
// pack -> att -> hwc(H,W,C natural-layout pure stores) -> comb(gather+W1+res) -> d -> fin
// h/w partials live INSIDE d_out (each 1KB x1 chunk = 512B h + 512B w), overwritten
// block-locally by k_comb's x1 writes. d_out also doubles as x1 between comb and fin.

typedef __attribute__((ext_vector_type(8))) short bf16x8;
typedef __attribute__((ext_vector_type(4))) float f32x4;
typedef __attribute__((ext_vector_type(4))) unsigned short u16x4;
typedef unsigned short u16;
typedef unsigned int u32;

#define DEV __device__ __forceinline__

DEV u16 f2b(float f) {  // fp32 -> bf16 RNE
  union { float f; u32 u; } v; v.f = f;
  u32 r = v.u + 0x7FFFu + ((v.u >> 16) & 1u);
  return (u16)(r >> 16);
}
DEV float b2f(u16 b) {
  union { u32 u; float f; } v; v.u = ((u32)b) << 16; return v.f;
}

// LDS tiles: [256 rows][256 bf16] = 128 KiB, row pitch 512B, XOR-swizzled 16B slots.
DEV int lds_off(int row, int colByte) {
  return (row << 9) + (colByte ^ ((row & 31) << 4));
}
DEV bf16x8 ld_lds(const u16* lds, int row, int colByte) {
  return *(const bf16x8*)((const char*)lds + lds_off(row, colByte));
}
DEV bf16x8 ld_glb(const u16* g, int row, int kByte) {  // row-major [256][256] bf16
  return *(const bf16x8*)((const char*)g + (row << 9) + kByte);
}

DEV void zero_acc(f32x4 acc[8][4]) {
#pragma unroll
  for (int i = 0; i < 8; ++i)
#pragma unroll
    for (int j = 0; j < 4; ++j) {
      acc[i][j][0] = 0.f; acc[i][j][1] = 0.f; acc[i][j][2] = 0.f; acc[i][j][3] = 0.f;
    }
}

// D[m][n] = sum_k P[m][k] * Q[n][k], M=N=K=256. 8 waves = 2(wm) x 4(wn).
template <typename LA, typename LB>
DEV void gemm256(LA loadA, LB loadB, f32x4 acc[8][4]) {
#pragma unroll
  for (int kk = 0; kk < 8; ++kk) {
    bf16x8 a[8], b[4];
#pragma unroll
    for (int i = 0; i < 8; ++i) a[i] = loadA(i, kk);
#pragma unroll
    for (int j = 0; j < 4; ++j) b[j] = loadB(j, kk);
#pragma unroll
    for (int i = 0; i < 8; ++i)
#pragma unroll
      for (int j = 0; j < 4; ++j)
        acc[i][j] = __builtin_amdgcn_mfma_f32_16x16x32_bf16(a[i], b[j], acc[i][j], 0, 0, 0);
  }
}

#define WAVE_SETUP                  \
  const int tid = threadIdx.x;      \
  const int lane = tid & 63;        \
  const int wave = tid >> 6;        \
  const int wm = wave >> 2;         \
  const int wn = wave & 3;          \
  const int lr = lane & 15;         \
  const int lk = lane >> 4;

// LDS-bounce epilogue: linear re-read of swizzled [256][256] bf16 tile -> wide stores.
// Caller stored element (p,c) at byte p*512 + (c*2 ^ ((p&31)<<4)).

// ---------- weight pack: WT[s][n*256+k] = W_s[k*256+n] (+I for s==7) ----------
__global__ void k_pack_all(const float* W0, const float* W1p, const float* W2p,
                           const float* W3p, const float* W4p, const float* W5p,
                           const float* W6p, const float* W7p, u16* __restrict__ WT) {
  int bi = blockIdx.x;
  int wsel = bi >> 8, n = bi & 255;
  const float* W;
  switch (wsel) {
    case 0: W = W0; break; case 1: W = W1p; break; case 2: W = W2p; break;
    case 3: W = W3p; break; case 4: W = W4p; break; case 5: W = W5p; break;
    case 6: W = W6p; break; default: W = W7p; break;
  }
  u16* dst = WT + wsel * 65536;
  int k0 = threadIdx.x * 4;
#pragma unroll
  for (int i = 0; i < 4; ++i) {
    int k = k0 + i;
    float v = W[k * 256 + n];
    if (wsel == 7 && k == n) v += 1.0f;
    dst[n * 256 + k] = f2b(v);
  }
}

// ---------- attention-block GEMM: D[p][c] = sum_q W_attn[q][p] X[q][c] (+b_attn[p]) ----------
__global__ __launch_bounds__(512, 2) void k_att(const float* __restrict__ x,
    const u16* __restrict__ WTattn, const float* __restrict__ b_attn,
    u16* __restrict__ S_att) {
  __shared__ alignas(16) u16 XT[65536];  // [c][q]
  WAVE_SETUP;
  const int t = blockIdx.x;
  const int d = t & 31, w1 = (t >> 5) & 1, h1 = (t >> 6) & 1, b = t >> 7;
  const int B0 = (((b * 32 + h1 * 16) * 32 + w1 * 16) * 32 + d) * 256;

  for (int i = tid; i < 16384; i += 512) {
    int q = i >> 6;
    int c4 = (i & 63) << 2;
    const float4 v = *(const float4*)(x + B0 + (q >> 4) * 262144 + (q & 15) * 8192 + c4);
    XT[lds_off(c4 + 0, q * 2) >> 1] = f2b(v.x);
    XT[lds_off(c4 + 1, q * 2) >> 1] = f2b(v.y);
    XT[lds_off(c4 + 2, q * 2) >> 1] = f2b(v.z);
    XT[lds_off(c4 + 3, q * 2) >> 1] = f2b(v.w);
  }
  __syncthreads();

  f32x4 acc[8][4];
  zero_acc(acc);
  gemm256(
      [&](int i, int kk) { return ld_glb(WTattn, wm * 128 + i * 16 + lr, kk * 64 + lk * 16); },
      [&](int j, int kk) { return ld_lds(XT, wn * 64 + j * 16 + lr, kk * 64 + lk * 16); },
      acc);

  __syncthreads();  // all XT reads done; reuse as output tile
#pragma unroll
  for (int i = 0; i < 8; ++i)
#pragma unroll
    for (int j = 0; j < 4; ++j)
#pragma unroll
      for (int r = 0; r < 4; ++r) {
        int p = wm * 128 + i * 16 + lk * 4 + r;
        int c = wn * 64 + j * 16 + lr;
        XT[lds_off(p, c * 2) >> 1] = f2b(acc[i][j][r] + b_attn[p]);
      }
  __syncthreads();
  u16* out = S_att + t * 65536;  // [p][c]
  for (int idx = tid; idx < 8192; idx += 512) {
    int p = idx >> 5, sB = (idx & 31) << 4;
    bf16x8 v = *(const bf16x8*)((const char*)XT + p * 512 + sB);
    int c8 = (sB ^ ((p & 31) << 4)) >> 1;
    *(bf16x8*)(out + p * 256 + c8) = v;
  }
}

// ---------- h + w + c GEMMs: natural-layout pure stores (no RMW) ----------
// h element (m,n): at d_out chunk(m) bytes [n*2, +2)        (first 512B of 1KB chunk)
// w element (m,n): at d_out chunk(m) bytes [512 + n*2, +2)  (second 512B)
// c element (m=pos,n=c): bf16 [pos][c] scratch via LDS bounce.
__global__ __launch_bounds__(512, 2) void k_hwc(const float* __restrict__ x,
    const u16* __restrict__ WTh, const u16* __restrict__ WTw, const u16* __restrict__ WTc,
    u16* __restrict__ c_out, char* __restrict__ hw) {
  __shared__ alignas(16) u16 XS[65536];  // [pos][c]
  WAVE_SETUP;
  const int t = blockIdx.x;
  const int d = t & 31, w1 = (t >> 5) & 1, h1 = (t >> 6) & 1, b = t >> 7;
  const int B0 = (((b * 32 + h1 * 16) * 32 + w1 * 16) * 32 + d) * 256;

  for (int i = tid; i < 16384; i += 512) {
    int pos = i >> 6;
    int c4 = (i & 63) << 2;
    const float4 v = *(const float4*)(x + B0 + (pos >> 4) * 262144 + (pos & 15) * 8192 + c4);
    u16x4 pk;
    pk[0] = f2b(v.x); pk[1] = f2b(v.y); pk[2] = f2b(v.z); pk[3] = f2b(v.w);
    *(u16x4*)((char*)XS + lds_off(pos, c4 * 2)) = pk;
  }
  __syncthreads();

  f32x4 acc[8][4];

  // phase H: m=(lc,lw) k=(lh',g'): A[m][k] = XS[khi*16+lw][lc*16+klo]
  zero_acc(acc);
  gemm256(
      [&](int i, int kk) {
        int k = kk * 32 + lk * 8;
        int khi = k >> 4, kloB = (k & 15) * 2;
        int mt = wm * 8 + i;
        return *(const bf16x8*)((const char*)XS + lds_off(khi * 16 + lr, mt * 32 + kloB));
      },
      [&](int j, int kk) { return ld_glb(WTh, wn * 64 + j * 16 + lr, kk * 64 + lk * 16); },
      acc);
#pragma unroll
  for (int i = 0; i < 8; ++i)
#pragma unroll
    for (int j = 0; j < 4; ++j)
#pragma unroll
      for (int r = 0; r < 4; ++r) {
        int m = wm * 128 + i * 16 + lk * 4 + r;
        int n = wn * 64 + j * 16 + lr;
        size_t cb = (size_t)(B0 + ((m >> 4) << 18) + ((m & 15) << 13)) * 4;
        *(u16*)(hw + cb + n * 2) = f2b(acc[i][j][r]);
      }

  // phase W: m=(lc,lh) k=(lw',g'): A[m][k] = XS[lh*16+khi][lc*16+klo]
  zero_acc(acc);
  gemm256(
      [&](int i, int kk) {
        int k = kk * 32 + lk * 8;
        int khi = k >> 4, kloB = (k & 15) * 2;
        int mt = wm * 8 + i;
        return *(const bf16x8*)((const char*)XS + lds_off(lr * 16 + khi, mt * 32 + kloB));
      },
      [&](int j, int kk) { return ld_glb(WTw, wn * 64 + j * 16 + lr, kk * 64 + lk * 16); },
      acc);
#pragma unroll
  for (int i = 0; i < 8; ++i)
#pragma unroll
    for (int j = 0; j < 4; ++j)
#pragma unroll
      for (int r = 0; r < 4; ++r) {
        int m = wm * 128 + i * 16 + lk * 4 + r;
        int n = wn * 64 + j * 16 + lr;
        size_t cb = (size_t)(B0 + ((m >> 4) << 18) + ((m & 15) << 13)) * 4;
        *(u16*)(hw + cb + 512 + n * 2) = f2b(acc[i][j][r]);
      }

  // phase C (identity layout): last user of XS -> LDS bounce -> wide stores
  zero_acc(acc);
  gemm256(
      [&](int i, int kk) { return ld_lds(XS, wm * 128 + i * 16 + lr, kk * 64 + lk * 16); },
      [&](int j, int kk) { return ld_glb(WTc, wn * 64 + j * 16 + lr, kk * 64 + lk * 16); },
      acc);
  __syncthreads();
#pragma unroll
  for (int i = 0; i < 8; ++i)
#pragma unroll
    for (int j = 0; j < 4; ++j)
#pragma unroll
      for (int r = 0; r < 4; ++r) {
        int m = wm * 128 + i * 16 + lk * 4 + r;
        int n = wn * 64 + j * 16 + lr;
        XS[lds_off(m, n * 2) >> 1] = f2b(acc[i][j][r]);
      }
  __syncthreads();
  u16* outc = c_out + t * 65536;
  for (int idx = tid; idx < 8192; idx += 512) {
    int p = idx >> 5, sB = (idx & 31) << 4;
    bf16x8 v = *(const bf16x8*)((const char*)XS + p * 512 + sB);
    int c8 = (sB ^ ((p & 31) << 4)) >> 1;
    *(bf16x8*)(outc + p * 256 + c8) = v;
  }
}

// ---------- combine + W1 + residual -> x1 (into d_out, overwriting h/w chunks) ----------
__global__ __launch_bounds__(512, 2) void k_comb(const float* __restrict__ x,
    const u16* __restrict__ S_att, const u16* __restrict__ c_out,
    const float* __restrict__ bh, const float* __restrict__ bw, const float* __restrict__ bc,
    const u16* __restrict__ WT1, const float* __restrict__ b1,
    float* __restrict__ x1) {
  __shared__ alignas(16) u16 OUT[65536];  // [pos][c]
  WAVE_SETUP;
  const int t = blockIdx.x;
  const int d = t & 31, w1 = (t >> 5) & 1, h1 = (t >> 6) & 1, b = t >> 7;
  const int B0 = (((b * 32 + h1 * 16) * 32 + w1 * 16) * 32 + d) * 256;
  const u16* att_t = S_att + t * 65536;
  const u16* c_t = c_out + t * 65536;
  const char* hwp = (const char*)x1;

  for (int i = tid; i < 16384; i += 512) {
    int pos = i >> 6;
    int c4 = (i & 63) << 2;
    u16x4 av = *(const u16x4*)(att_t + pos * 256 + c4);
    u16x4 cv = *(const u16x4*)(c_t + pos * 256 + c4);
    // h: m=(c>>4)*16+(pos&15), n=(pos>>4)*16+(c&15)
    int mh = ((c4 >> 4) << 4) + (pos & 15);
    int nh = ((pos >> 4) << 4) + (c4 & 15);
    size_t cbh = (size_t)(B0 + ((mh >> 4) << 18) + ((mh & 15) << 13)) * 4;
    u16x4 hv = *(const u16x4*)(hwp + cbh + nh * 2);
    // w: m=(c>>4)*16+(pos>>4), n=(pos&15)*16+(c&15)
    int mw = ((c4 >> 4) << 4) + (pos >> 4);
    int nw = ((pos & 15) << 4) + (c4 & 15);
    size_t cbw = (size_t)(B0 + ((mw >> 4) << 18) + ((mw & 15) << 13)) * 4;
    u16x4 wv = *(const u16x4*)(hwp + cbw + 512 + nw * 2);
    int lh = pos >> 4, lw = pos & 15;
    u16x4 o;
#pragma unroll
    for (int j = 0; j < 4; ++j) {
      int c = c4 + j;
      float hwv = b2f(cv[j]) + b2f(hv[j]) + b2f(wv[j]) +
                  bh[lh * 16 + (c & 15)] + bw[lw * 16 + (c & 15)] + bc[c];
      o[j] = f2b((1.0f + b2f(av[j])) * hwv);
    }
    *(u16x4*)((char*)OUT + lds_off(pos, c4 * 2)) = o;
  }
  __syncthreads();

  f32x4 acc[8][4];
  zero_acc(acc);
  gemm256(
      [&](int i, int kk) { return ld_lds(OUT, wm * 128 + i * 16 + lr, kk * 64 + lk * 16); },
      [&](int j, int kk) { return ld_glb(WT1, wn * 64 + j * 16 + lr, kk * 64 + lk * 16); },
      acc);
#pragma unroll
  for (int i = 0; i < 8; ++i)
#pragma unroll
    for (int j = 0; j < 4; ++j)
#pragma unroll
      for (int r = 0; r < 4; ++r) {
        int m = wm * 128 + i * 16 + lk * 4 + r;
        int n = wn * 64 + j * 16 + lr;
        int g = B0 + (m >> 4) * 262144 + (m & 15) * 8192 + n;
        x1[g] = x[g] + acc[i][j][r] + b1[n];
      }
}

// ---------- d-block gather GEMM ----------
__global__ __launch_bounds__(512, 2) void k_d(const float* __restrict__ x1,
    const u16* __restrict__ WTd, const float* __restrict__ bd, u16* __restrict__ xd) {
  __shared__ alignas(16) u16 XS[65536];  // rows R=(wlo,ld), cols c
  WAVE_SETUP;
  const int t = blockIdx.x;
  const int d1 = t & 1, wb = (t >> 1) & 1, h = (t >> 2) & 31, b = t >> 7;
  const int B0 = (((b * 32 + h) * 32 + wb * 16) * 32 + d1 * 16) * 256;

  for (int i = tid; i < 16384; i += 512) {
    int R = i >> 6;
    int c4 = (i & 63) << 2;
    const float4 v = *(const float4*)(x1 + B0 + (R >> 4) * 8192 + (R & 15) * 256 + c4);
    u16x4 pk;
    pk[0] = f2b(v.x); pk[1] = f2b(v.y); pk[2] = f2b(v.z); pk[3] = f2b(v.w);
    *(u16x4*)((char*)XS + lds_off(R, c4 * 2)) = pk;
  }
  __syncthreads();

  f32x4 acc[8][4];
  zero_acc(acc);
  // m=(wlo,lc) k=(ld',g'): A[m][k] = XS[wlo*16+khi][lc*16+klo]
  gemm256(
      [&](int i, int kk) {
        int k = kk * 32 + lk * 8;
        int khi = k >> 4, kloB = (k & 15) * 2;
        int mt = wm * 8 + i;
        return *(const bf16x8*)((const char*)XS + lds_off(mt * 16 + khi, lr * 32 + kloB));
      },
      [&](int j, int kk) { return ld_glb(WTd, wn * 64 + j * 16 + lr, kk * 64 + lk * 16); },
      acc);
  __syncthreads();
  // bounce: element (m,n) -> R=(m>>4)*16+(n>>4), cc=(m&15)*16+(n&15)
#pragma unroll
  for (int i = 0; i < 8; ++i)
#pragma unroll
    for (int j = 0; j < 4; ++j)
#pragma unroll
      for (int r = 0; r < 4; ++r) {
        int m = wm * 128 + i * 16 + lk * 4 + r;
        int n = wn * 64 + j * 16 + lr;
        int R = ((m >> 4) << 4) + (n >> 4);
        int cc = ((m & 15) << 4) + (n & 15);
        XS[lds_off(R, cc * 2) >> 1] = f2b(acc[i][j][r] + bd[n]);
      }
  __syncthreads();
  for (int idx = tid; idx < 8192; idx += 512) {
    int R = idx >> 5, sB = (idx & 31) << 4;
    bf16x8 v = *(const bf16x8*)((const char*)XS + R * 512 + sB);
    int c8 = (sB ^ ((R & 31) << 4)) >> 1;
    *(bf16x8*)(xd + B0 + ((R >> 4) << 13) + ((R & 15) << 8) + c8) = v;
  }
}

// ---------- W2 + residual, then (W3+I) + b3 -> final ----------
__global__ __launch_bounds__(512, 2) void k_fin(const float* x1,
    const u16* __restrict__ xd, const u16* __restrict__ WT2, const u16* __restrict__ WT3p,
    const float* __restrict__ b2, const float* __restrict__ b3, float* outp) {
  __shared__ alignas(16) u16 X2[65536];
  WAVE_SETUP;
  const int vt = blockIdx.x;
  const int base = vt * 65536;
  const u16* xd_t = xd + base;

  f32x4 acc[8][4];
  zero_acc(acc);
  gemm256(
      [&](int i, int kk) { return ld_glb(xd_t, wm * 128 + i * 16 + lr, kk * 64 + lk * 16); },
      [&](int j, int kk) { return ld_glb(WT2, wn * 64 + j * 16 + lr, kk * 64 + lk * 16); },
      acc);
#pragma unroll
  for (int i = 0; i < 8; ++i)
#pragma unroll
    for (int j = 0; j < 4; ++j)
#pragma unroll
      for (int r = 0; r < 4; ++r) {
        int m = wm * 128 + i * 16 + lk * 4 + r;
        int n = wn * 64 + j * 16 + lr;
        float v = x1[base + m * 256 + n] + acc[i][j][r] + b2[n];
        X2[lds_off(m, n * 2) >> 1] = f2b(v);
      }
  __syncthreads();

  zero_acc(acc);
  gemm256(
      [&](int i, int kk) { return ld_lds(X2, wm * 128 + i * 16 + lr, kk * 64 + lk * 16); },
      [&](int j, int kk) { return ld_glb(WT3p, wn * 64 + j * 16 + lr, kk * 64 + lk * 16); },
      acc);
#pragma unroll
  for (int i = 0; i < 8; ++i)
#pragma unroll
    for (int j = 0; j < 4; ++j)
#pragma unroll
      for (int r = 0; r < 4; ++r) {
        int m = wm * 128 + i * 16 + lk * 4 + r;
        int n = wn * 64 + j * 16 + lr;
        outp[base + m * 256 + n] = acc[i][j][r] + b3[n];
      }
}

extern "C" void kernel_launch(void* const* d_in, const int* in_sizes, int n_in,
                              void* d_out, int out_size, void* d_ws, size_t ws_size,
                              hipStream_t stream) {
  (void)in_sizes; (void)n_in; (void)out_size; (void)ws_size;
  const float* x      = (const float*)d_in[0];
  const float* W_h    = (const float*)d_in[1];
  const float* b_h    = (const float*)d_in[2];
  const float* W_w    = (const float*)d_in[3];
  const float* b_w    = (const float*)d_in[4];
  const float* W_c    = (const float*)d_in[5];
  const float* b_c    = (const float*)d_in[6];
  const float* W_d    = (const float*)d_in[7];
  const float* b_d    = (const float*)d_in[8];
  const float* W_attn = (const float*)d_in[9];
  const float* b_attn = (const float*)d_in[10];
  const float* W_1    = (const float*)d_in[11];
  const float* b_1    = (const float*)d_in[12];
  const float* W_2    = (const float*)d_in[13];
  const float* b_2    = (const float*)d_in[14];
  const float* W_3    = (const float*)d_in[15];
  const float* b_3    = (const float*)d_in[16];
  float* outp = (float*)d_out;

  u16* WT    = (u16*)d_ws;          // 8 * 65536 bf16 (1 MiB)
  u16* S_att = WT + 8 * 65536;      // 33.5M bf16 (64 MiB)
  u16* c_out = S_att + 33554432;    // 33.5M bf16 (64 MiB)
  u16* xd    = S_att;               // overlay: S_att dead after k_comb

  // slots: 0:h 1:w 2:c 3:attn 4:W1 5:Wd 6:W2 7:W3(+I)
  k_pack_all<<<2048, 64, 0, stream>>>(W_h, W_w, W_c, W_attn, W_1, W_d, W_2, W_3, WT);

  k_att <<<512, 512, 0, stream>>>(x, WT + 3 * 65536, b_attn, S_att);
  k_hwc <<<512, 512, 0, stream>>>(x, WT + 0 * 65536, WT + 1 * 65536, WT + 2 * 65536,
                                  c_out, (char*)outp);
  k_comb<<<512, 512, 0, stream>>>(x, S_att, c_out, b_h, b_w, b_c, WT + 4 * 65536, b_1, outp);
  k_d   <<<512, 512, 0, stream>>>(outp, WT + 5 * 65536, b_d, xd);
  k_fin <<<512, 512, 0, stream>>>(outp, xd, WT + 6 * 65536, WT + 7 * 65536, b_2, b_3, outp);
}

// Round 3
// 643.917 us; speedup vs baseline: 1.7561x; 1.1477x over previous
//
#include <hip/hip_runtime.h>

// MLPP: 8x 256x256 GEMMs over gathered views of x[4,32,32,32,256] (fp32 in/out).
// pack -> att(c-half) -> hw(full tile) -> comb(c-GEMM+combine+W1, pos-half)
//      -> d(wlo-half) -> fin(W2,res,W3+I, pos-half)
// Regions: WT(1MiB) | R1: att -> x1_blk bf16 (t-blocked) | R2: xd bf16 (x-layout)
// d_out: h/w natural-layout partials -> final fp32 output.

typedef __attribute__((ext_vector_type(8))) short bf16x8;
typedef __attribute__((ext_vector_type(8))) unsigned short u16x8;
typedef __attribute__((ext_vector_type(4))) float f32x4;
typedef __attribute__((ext_vector_type(4))) unsigned short u16x4;
typedef unsigned short u16;
typedef unsigned int u32;

#define DEV __device__ __forceinline__

DEV u16 f2b(float f) {  // fp32 -> bf16 RNE
  union { float f; u32 u; } v; v.f = f;
  u32 r = v.u + 0x7FFFu + ((v.u >> 16) & 1u);
  return (u16)(r >> 16);
}
DEV float b2f(u16 b) {
  union { u32 u; float f; } v; v.u = ((u32)b) << 16; return v.f;
}

// 512B-pitch LDS tiles, XOR swizzle over 16B slots (32 slots/row).
DEV int lds_off(int row, int colByte) {
  return (row << 9) + (colByte ^ ((row & 31) << 4));
}
// 256B-pitch tiles (16 slots/row).
DEV int lds_off256(int row, int colByte) {
  return (row << 8) + (colByte ^ ((row & 15) << 4));
}
DEV bf16x8 ld_lds(const u16* lds, int row, int colByte) {
  return *(const bf16x8*)((const char*)lds + lds_off(row, colByte));
}
DEV bf16x8 ld_glb(const u16* g, int row, int kByte) {  // row-major [.][256] bf16
  return *(const bf16x8*)((const char*)g + (row << 9) + kByte);
}

template <int MI, int NJ>
DEV void zero_acc(f32x4 acc[MI][NJ]) {
#pragma unroll
  for (int i = 0; i < MI; ++i)
#pragma unroll
    for (int j = 0; j < NJ; ++j) {
      acc[i][j][0] = 0.f; acc[i][j][1] = 0.f; acc[i][j][2] = 0.f; acc[i][j][3] = 0.f;
    }
}

// D[m][n] = sum_k P[m][k] * Q[n][k], K=256. MI/NJ = 16x16 tiles per wave.
template <int MI, int NJ, typename LA, typename LB>
DEV void gemmT(LA loadA, LB loadB, f32x4 acc[MI][NJ]) {
#pragma unroll
  for (int kk = 0; kk < 8; ++kk) {
    bf16x8 a[MI], b[NJ];
#pragma unroll
    for (int i = 0; i < MI; ++i) a[i] = loadA(i, kk);
#pragma unroll
    for (int j = 0; j < NJ; ++j) b[j] = loadB(j, kk);
#pragma unroll
    for (int i = 0; i < MI; ++i)
#pragma unroll
      for (int j = 0; j < NJ; ++j)
        acc[i][j] = __builtin_amdgcn_mfma_f32_16x16x32_bf16(a[i], b[j], acc[i][j], 0, 0, 0);
  }
}

#define WAVE_SETUP                  \
  const int tid = threadIdx.x;      \
  const int lane = tid & 63;        \
  const int wave = tid >> 6;        \
  const int wm = wave >> 2;         \
  const int wn = wave & 3;          \
  const int lr = lane & 15;         \
  const int lk = lane >> 4;

// ---------- weight pack: WT[s][n*256+k] = W_s[k*256+n] (+I for s==7) ----------
__global__ void k_pack_all(const float* W0, const float* W1p, const float* W2p,
                           const float* W3p, const float* W4p, const float* W5p,
                           const float* W6p, const float* W7p, u16* __restrict__ WT) {
  int bi = blockIdx.x;
  int wsel = bi >> 8, n = bi & 255;
  const float* W;
  switch (wsel) {
    case 0: W = W0; break; case 1: W = W1p; break; case 2: W = W2p; break;
    case 3: W = W3p; break; case 4: W = W4p; break; case 5: W = W5p; break;
    case 6: W = W6p; break; default: W = W7p; break;
  }
  u16* dst = WT + wsel * 65536;
  int k0 = threadIdx.x * 4;
#pragma unroll
  for (int i = 0; i < 4; ++i) {
    int k = k0 + i;
    float v = W[k * 256 + n];
    if (wsel == 7 && k == n) v += 1.0f;
    dst[n * 256 + k] = f2b(v);
  }
}

// ---------- att: D[p][c] = sum_q Wa[q][p] X[q][c] (+b_attn[p]); c-half blocks ----------
__global__ __launch_bounds__(512, 4) void k_att(const float* __restrict__ x,
    const u16* __restrict__ WTattn, const float* __restrict__ b_attn,
    u16* __restrict__ att) {
  __shared__ alignas(16) u16 XT[32768];  // [c-half 128][q 256], 64 KiB
  WAVE_SETUP;
  const int ch = blockIdx.x & 1;
  const int t = blockIdx.x >> 1;
  const int d = t & 31, w1 = (t >> 5) & 1, h1 = (t >> 6) & 1, b = t >> 7;
  const int B0 = (((b * 32 + h1 * 16) * 32 + w1 * 16) * 32 + d) * 256;

  // transpose-stage half of the channels
  for (int i = tid; i < 8192; i += 512) {
    int q = i >> 5;
    int c4 = (i & 31) << 2;
    const float4 v = *(const float4*)(x + B0 + (q >> 4) * 262144 + (q & 15) * 8192 + ch * 128 + c4);
    XT[lds_off(c4 + 0, q * 2) >> 1] = f2b(v.x);
    XT[lds_off(c4 + 1, q * 2) >> 1] = f2b(v.y);
    XT[lds_off(c4 + 2, q * 2) >> 1] = f2b(v.z);
    XT[lds_off(c4 + 3, q * 2) >> 1] = f2b(v.w);
  }
  __syncthreads();

  f32x4 acc[8][2];
  zero_acc<8, 2>(acc);
  gemmT<8, 2>(
      [&](int i, int kk) { return ld_glb(WTattn, wm * 128 + i * 16 + lr, kk * 64 + lk * 16); },
      [&](int j, int kk) { return ld_lds(XT, wn * 32 + j * 16 + lr, kk * 64 + lk * 16); },
      acc);

  __syncthreads();  // XT dead; reuse as [p 256][c-half 128] bounce tile (256B pitch)
#pragma unroll
  for (int i = 0; i < 8; ++i)
#pragma unroll
    for (int j = 0; j < 2; ++j)
#pragma unroll
      for (int r = 0; r < 4; ++r) {
        int p = wm * 128 + i * 16 + lk * 4 + r;
        int cl = wn * 32 + j * 16 + lr;
        XT[lds_off256(p, cl * 2) >> 1] = f2b(acc[i][j][r] + b_attn[p]);
      }
  __syncthreads();
  u16* out = att + t * 65536;
  for (int i = tid; i < 4096; i += 512) {
    int p = i >> 4, sB = (i & 15) << 4;
    bf16x8 v = *(const bf16x8*)((const char*)XT + p * 256 + sB);
    int c8l = (sB ^ ((p & 15) << 4)) >> 1;
    *(bf16x8*)(out + p * 256 + ch * 128 + c8l) = v;
  }
}

// ---------- h + w GEMMs: natural-layout pure stores into d_out chunks ----------
// h element (m,n): chunk(m) bytes [n*2, +2); w element (m,n): chunk(m) bytes [512+n*2, +2)
__global__ __launch_bounds__(512, 2) void k_hw(const float* __restrict__ x,
    const u16* __restrict__ WTh, const u16* __restrict__ WTw, char* __restrict__ hw) {
  __shared__ alignas(16) u16 XS[65536];  // [pos 256][c 256], 128 KiB
  WAVE_SETUP;
  const int t = blockIdx.x;
  const int d = t & 31, w1 = (t >> 5) & 1, h1 = (t >> 6) & 1, b = t >> 7;
  const int B0 = (((b * 32 + h1 * 16) * 32 + w1 * 16) * 32 + d) * 256;

  for (int i = tid; i < 16384; i += 512) {
    int pos = i >> 6;
    int c4 = (i & 63) << 2;
    const float4 v = *(const float4*)(x + B0 + (pos >> 4) * 262144 + (pos & 15) * 8192 + c4);
    u16x4 pk;
    pk[0] = f2b(v.x); pk[1] = f2b(v.y); pk[2] = f2b(v.z); pk[3] = f2b(v.w);
    *(u16x4*)((char*)XS + lds_off(pos, c4 * 2)) = pk;
  }
  __syncthreads();

  f32x4 acc[8][4];

  // phase H: m=(lc,lw) k=(lh',g'): A[m][k] = XS[khi*16+lw][lc*16+klo]
  zero_acc<8, 4>(acc);
  gemmT<8, 4>(
      [&](int i, int kk) {
        int k = kk * 32 + lk * 8;
        int khi = k >> 4, kloB = (k & 15) * 2;
        int mt = wm * 8 + i;
        return *(const bf16x8*)((const char*)XS + lds_off(khi * 16 + lr, mt * 32 + kloB));
      },
      [&](int j, int kk) { return ld_glb(WTh, wn * 64 + j * 16 + lr, kk * 64 + lk * 16); },
      acc);
#pragma unroll
  for (int i = 0; i < 8; ++i)
#pragma unroll
    for (int j = 0; j < 4; ++j)
#pragma unroll
      for (int r = 0; r < 4; ++r) {
        int m = wm * 128 + i * 16 + lk * 4 + r;
        int n = wn * 64 + j * 16 + lr;
        size_t cb = (size_t)(B0 + ((m >> 4) << 18) + ((m & 15) << 13)) * 4;
        *(u16*)(hw + cb + n * 2) = f2b(acc[i][j][r]);
      }

  // phase W: m=(lc,lh) k=(lw',g'): A[m][k] = XS[lh*16+khi][lc*16+klo]
  zero_acc<8, 4>(acc);
  gemmT<8, 4>(
      [&](int i, int kk) {
        int k = kk * 32 + lk * 8;
        int khi = k >> 4, kloB = (k & 15) * 2;
        int mt = wm * 8 + i;
        return *(const bf16x8*)((const char*)XS + lds_off(lr * 16 + khi, mt * 32 + kloB));
      },
      [&](int j, int kk) { return ld_glb(WTw, wn * 64 + j * 16 + lr, kk * 64 + lk * 16); },
      acc);
#pragma unroll
  for (int i = 0; i < 8; ++i)
#pragma unroll
    for (int j = 0; j < 4; ++j)
#pragma unroll
      for (int r = 0; r < 4; ++r) {
        int m = wm * 128 + i * 16 + lk * 4 + r;
        int n = wn * 64 + j * 16 + lr;
        size_t cb = (size_t)(B0 + ((m >> 4) << 18) + ((m & 15) << 13)) * 4;
        *(u16*)(hw + cb + 512 + n * 2) = f2b(acc[i][j][r]);
      }
}

// ---------- comb: c-GEMM + combine(h,w,att via wide RMW) + W1 + x residual -> x1_blk ----------
__global__ __launch_bounds__(512, 4) void k_comb(const float* __restrict__ x,
    const char* __restrict__ hw, const u16* __restrict__ att_and_x1,
    const float* __restrict__ bh, const float* __restrict__ bw, const float* __restrict__ bc,
    const u16* __restrict__ WTc, const u16* __restrict__ WT1, const float* __restrict__ b1,
    u16* __restrict__ x1_blk) {
  __shared__ alignas(16) u16 XS[32768];  // [pos-half 128][c 256], 64 KiB; multi-use
  WAVE_SETUP;
  const int ph = blockIdx.x & 1;
  const int t = blockIdx.x >> 1;
  const int d = t & 31, w1 = (t >> 5) & 1, h1 = (t >> 6) & 1, b = t >> 7;
  const int B0 = (((b * 32 + h1 * 16) * 32 + w1 * 16) * 32 + d) * 256;

  // 1. stage x (bf16) for this pos-half
  for (int i = tid; i < 8192; i += 512) {
    int posl = i >> 6;
    int c4 = (i & 63) << 2;
    int pos = ph * 128 + posl;
    const float4 v = *(const float4*)(x + B0 + (pos >> 4) * 262144 + (pos & 15) * 8192 + c4);
    u16x4 pk;
    pk[0] = f2b(v.x); pk[1] = f2b(v.y); pk[2] = f2b(v.z); pk[3] = f2b(v.w);
    *(u16x4*)((char*)XS + lds_off(posl, c4 * 2)) = pk;
  }
  __syncthreads();

  // 2. c-GEMM: D[posl][c'] = sum_c X[posl][c] Wc[c][c']
  f32x4 acc[4][4];
  zero_acc<4, 4>(acc);
  gemmT<4, 4>(
      [&](int i, int kk) { return ld_lds(XS, wm * 64 + i * 16 + lr, kk * 64 + lk * 16); },
      [&](int j, int kk) { return ld_glb(WTc, wn * 64 + j * 16 + lr, kk * 64 + lk * 16); },
      acc);
  __syncthreads();  // all XS reads done

  // 3. overwrite XS <- acc_c + biases
#pragma unroll
  for (int i = 0; i < 4; ++i)
#pragma unroll
    for (int j = 0; j < 4; ++j)
#pragma unroll
      for (int r = 0; r < 4; ++r) {
        int mloc = wm * 64 + i * 16 + lk * 4 + r;
        int n = wn * 64 + j * 16 + lr;
        int lh = ph * 8 + wm * 4 + i;   // (ph*128+mloc)>>4
        int lw = lk * 4 + r;            // mloc&15
        float v = acc[i][j][r] + bc[n] + bh[lh * 16 + (n & 15)] + bw[lw * 16 + (n & 15)];
        XS[lds_off(mloc, n * 2) >> 1] = f2b(v);
      }
  __syncthreads();

  // 4. h-RMW: h[mh][nh] += into XS[pos][c]; wide on both sides
  for (int i2 = tid; i2 < 4096; i2 += 512) {
    int mh = i2 >> 4;
    int nh8 = ph * 128 + ((i2 & 15) << 3);
    size_t cb = (size_t)(B0 + ((mh >> 4) << 18) + ((mh & 15) << 13)) * 4;
    u16x8 hv = *(const u16x8*)(hw + cb + nh8 * 2);
    int posl = ((nh8 >> 4) << 4) + (mh & 15) - ph * 128;
    int c8 = ((mh >> 4) << 4) + (nh8 & 15);
    u16x8* p = (u16x8*)((char*)XS + lds_off(posl, c8 * 2));
    u16x8 cur = *p, o;
#pragma unroll
    for (int j = 0; j < 8; ++j) o[j] = f2b(b2f(cur[j]) + b2f(hv[j]));
    *p = o;
  }
  __syncthreads();

  // 5. w-RMW
  for (int i2 = tid; i2 < 4096; i2 += 512) {
    int mwi = i2 >> 5;                   // 0..127: (c_hi, lhLoc)
    int nw8 = (i2 & 31) << 3;            // 0..255
    int c_hi = mwi >> 3, lhLoc = mwi & 7;
    int mw = c_hi * 16 + ph * 8 + lhLoc;
    size_t cb = (size_t)(B0 + ((mw >> 4) << 18) + ((mw & 15) << 13)) * 4;
    u16x8 wv = *(const u16x8*)(hw + cb + 512 + nw8 * 2);
    int posl = lhLoc * 16 + (nw8 >> 4);
    int c8 = c_hi * 16 + (nw8 & 15);
    u16x8* p = (u16x8*)((char*)XS + lds_off(posl, c8 * 2));
    u16x8 cur = *p, o;
#pragma unroll
    for (int j = 0; j < 8; ++j) o[j] = f2b(b2f(cur[j]) + b2f(wv[j]));
    *p = o;
  }
  __syncthreads();

  // 6. att-RMW: XS = (1+att)*XS
  {
    const u16* att_t = att_and_x1 + t * 65536;
    for (int i2 = tid; i2 < 4096; i2 += 512) {
      int posl = i2 >> 5;
      int c8 = (i2 & 31) << 3;
      u16x8 av = *(const u16x8*)(att_t + (ph * 128 + posl) * 256 + c8);
      u16x8* p = (u16x8*)((char*)XS + lds_off(posl, c8 * 2));
      u16x8 cur = *p, o;
#pragma unroll
      for (int j = 0; j < 8; ++j) o[j] = f2b((1.0f + b2f(av[j])) * b2f(cur[j]));
      *p = o;
    }
  }
  __syncthreads();

  // 7. W1-GEMM
  zero_acc<4, 4>(acc);
  gemmT<4, 4>(
      [&](int i, int kk) { return ld_lds(XS, wm * 64 + i * 16 + lr, kk * 64 + lk * 16); },
      [&](int j, int kk) { return ld_glb(WT1, wn * 64 + j * 16 + lr, kk * 64 + lk * 16); },
      acc);
  __syncthreads();  // XS dead

  // 8. bounce acc+b1 into XS
#pragma unroll
  for (int i = 0; i < 4; ++i)
#pragma unroll
    for (int j = 0; j < 4; ++j)
#pragma unroll
      for (int r = 0; r < 4; ++r) {
        int mloc = wm * 64 + i * 16 + lk * 4 + r;
        int n = wn * 64 + j * 16 + lr;
        XS[lds_off(mloc, n * 2) >> 1] = f2b(acc[i][j][r] + b1[n]);
      }
  __syncthreads();

  // 9. x1 = x(fp32, coalesced) + ip; wide store to x1_blk (overwrites att[t] pos-half)
  u16* x1out = (u16*)att_and_x1 + t * 65536;
  for (int i = tid; i < 4096; i += 512) {
    int posl = i >> 5, sB = (i & 31) << 4;
    bf16x8 v = *(const bf16x8*)((const char*)XS + posl * 512 + sB);
    int c8 = (sB ^ ((posl & 31) << 4)) >> 1;
    int pos = ph * 128 + posl;
    const float* gx = x + B0 + (pos >> 4) * 262144 + (pos & 15) * 8192 + c8;
    float4 f0 = *(const float4*)gx;
    float4 f1 = *(const float4*)(gx + 4);
    u16x8 o;
    o[0] = f2b(b2f((u16)v[0]) + f0.x); o[1] = f2b(b2f((u16)v[1]) + f0.y);
    o[2] = f2b(b2f((u16)v[2]) + f0.z); o[3] = f2b(b2f((u16)v[3]) + f0.w);
    o[4] = f2b(b2f((u16)v[4]) + f1.x); o[5] = f2b(b2f((u16)v[5]) + f1.y);
    o[6] = f2b(b2f((u16)v[6]) + f1.z); o[7] = f2b(b2f((u16)v[7]) + f1.w);
    *(u16x8*)(x1out + pos * 256 + c8) = o;
  }
  (void)x1_blk;
}

// ---------- d-block gather GEMM (wlo-half blocks) ----------
__global__ __launch_bounds__(512, 4) void k_d(const u16* __restrict__ x1_blk,
    const u16* __restrict__ WTd, const float* __restrict__ bd, u16* __restrict__ xd) {
  __shared__ alignas(16) u16 XS[32768];  // [R 128][c 256]: R=(wloLoc,ld)
  WAVE_SETUP;
  const int bid = blockIdx.x;
  const int wh = bid & 1, d1 = (bid >> 1) & 1, wb = (bid >> 2) & 1,
            h = (bid >> 3) & 31, b = bid >> 8;
  const int tbase = b * 128 + (h >> 4) * 64 + wb * 32 + d1 * 16;
  const int posbase = (h & 15) * 16 + wh * 8;

  for (int i = tid; i < 4096; i += 512) {
    int Rl = i >> 5;              // wloLoc*16 + ld
    int c8 = (i & 31) << 3;
    int wloLoc = Rl >> 4, ld = Rl & 15;
    const u16x8 v = *(const u16x8*)(x1_blk + (size_t)(tbase + ld) * 65536 +
                                    (posbase + wloLoc) * 256 + c8);
    *(u16x8*)((char*)XS + lds_off(Rl, c8 * 2)) = v;
  }
  __syncthreads();

  f32x4 acc[4][4];
  zero_acc<4, 4>(acc);
  // m=(wloLoc,lc) k=(ld,g): A[m][k] = XS[(m>>4)*16+ld][lc*16+g]
  gemmT<4, 4>(
      [&](int i, int kk) {
        int k = kk * 32 + lk * 8;
        int khi = k >> 4, kloB = (k & 15) * 2;
        int mt = wm * 4 + i;
        return *(const bf16x8*)((const char*)XS + lds_off(mt * 16 + khi, lr * 32 + kloB));
      },
      [&](int j, int kk) { return ld_glb(WTd, wn * 64 + j * 16 + lr, kk * 64 + lk * 16); },
      acc);
  __syncthreads();
  // bounce: (mloc,n) -> row=(mloc>>4)*16+(n>>4), col=(mloc&15)*16+(n&15)
#pragma unroll
  for (int i = 0; i < 4; ++i)
#pragma unroll
    for (int j = 0; j < 4; ++j)
#pragma unroll
      for (int r = 0; r < 4; ++r) {
        int mloc = wm * 64 + i * 16 + lk * 4 + r;
        int n = wn * 64 + j * 16 + lr;
        int row = ((mloc >> 4) << 4) + (n >> 4);
        int col = ((mloc & 15) << 4) + (n & 15);
        XS[lds_off(row, col * 2) >> 1] = f2b(acc[i][j][r] + bd[n]);
      }
  __syncthreads();
  const int B0d = (((b * 32 + h) * 32 + wb * 16) * 32 + d1 * 16) * 256;
  for (int i = tid; i < 4096; i += 512) {
    int Rl = i >> 5, sB = (i & 31) << 4;
    bf16x8 v = *(const bf16x8*)((const char*)XS + Rl * 512 + sB);
    int c8 = (sB ^ ((Rl & 31) << 4)) >> 1;
    *(bf16x8*)(xd + B0d + (wh * 8 + (Rl >> 4)) * 8192 + (Rl & 15) * 256 + c8) = v;
  }
}

// ---------- fin: x2 = x1 + xd*W2 + b2; out = x2*(W3+I) + b3 (pos-half blocks) ----------
__global__ __launch_bounds__(512, 4) void k_fin(const u16* __restrict__ x1_blk,
    const u16* __restrict__ xd, const u16* __restrict__ WT2, const u16* __restrict__ WT3p,
    const float* __restrict__ b2, const float* __restrict__ b3, float* __restrict__ outp) {
  __shared__ alignas(16) u16 X2[32768];  // [128][256] bf16; later f32 bounce [64][256]
  WAVE_SETUP;
  const int ph = blockIdx.x & 1;
  const int vt = blockIdx.x >> 1;
  const int b = vt >> 7, h = (vt >> 2) & 31, w_hi = vt & 3;
  const size_t base = (size_t)vt * 65536;

  // stage x1 rows into X2 (wide); x1_blk is t-blocked
  for (int i = tid; i < 4096; i += 512) {
    int Rl = i >> 5, c8 = (i & 31) << 3;
    int rglob = ph * 128 + Rl;
    int w = w_hi * 8 + (rglob >> 5), d = rglob & 31;
    int t = b * 128 + (h >> 4) * 64 + (w >> 4) * 32 + d;
    int pos = (h & 15) * 16 + (w & 15);
    const u16x8 v = *(const u16x8*)(x1_blk + (size_t)t * 65536 + pos * 256 + c8);
    *(u16x8*)((char*)X2 + lds_off(Rl, c8 * 2)) = v;
  }

  // GEMM1: xd * W2 (A from global)
  const u16* xd_t = xd + base;
  f32x4 acc[4][4];
  zero_acc<4, 4>(acc);
  gemmT<4, 4>(
      [&](int i, int kk) { return ld_glb(xd_t, ph * 128 + wm * 64 + i * 16 + lr, kk * 64 + lk * 16); },
      [&](int j, int kk) { return ld_glb(WT2, wn * 64 + j * 16 + lr, kk * 64 + lk * 16); },
      acc);
  __syncthreads();

  // X2 = bf16(x1 + acc + b2)
#pragma unroll
  for (int i = 0; i < 4; ++i)
#pragma unroll
    for (int j = 0; j < 4; ++j)
#pragma unroll
      for (int r = 0; r < 4; ++r) {
        int mloc = wm * 64 + i * 16 + lk * 4 + r;
        int n = wn * 64 + j * 16 + lr;
        int off = lds_off(mloc, n * 2) >> 1;
        X2[off] = f2b(b2f(X2[off]) + acc[i][j][r] + b2[n]);
      }
  __syncthreads();

  // GEMM2: X2 * (W3+I)
  zero_acc<4, 4>(acc);
  gemmT<4, 4>(
      [&](int i, int kk) { return ld_lds(X2, wm * 64 + i * 16 + lr, kk * 64 + lk * 16); },
      [&](int j, int kk) { return ld_glb(WT3p, wn * 64 + j * 16 + lr, kk * 64 + lk * 16); },
      acc);

  // fp32 output via 2-round LDS bounce (64 rows each), float4 stores
  float* X2f = (float*)X2;
#pragma unroll
  for (int half = 0; half < 2; ++half) {
    __syncthreads();
    if (wm == half) {
#pragma unroll
      for (int i = 0; i < 4; ++i)
#pragma unroll
        for (int j = 0; j < 4; ++j)
#pragma unroll
          for (int r = 0; r < 4; ++r) {
            int row = i * 16 + lk * 4 + r;
            int n = wn * 64 + j * 16 + lr;
            X2f[row * 256 + n] = acc[i][j][r] + b3[n];
          }
    }
    __syncthreads();
    for (int i = tid; i < 4096; i += 512) {
      int row = i >> 6, c4 = (i & 63) << 2;
      f32x4 v = *(const f32x4*)(X2f + row * 256 + c4);
      *(f32x4*)(outp + base + (size_t)(ph * 128 + half * 64 + row) * 256 + c4) = v;
    }
  }
}

extern "C" void kernel_launch(void* const* d_in, const int* in_sizes, int n_in,
                              void* d_out, int out_size, void* d_ws, size_t ws_size,
                              hipStream_t stream) {
  (void)in_sizes; (void)n_in; (void)out_size; (void)ws_size;
  const float* x      = (const float*)d_in[0];
  const float* W_h    = (const float*)d_in[1];
  const float* b_h    = (const float*)d_in[2];
  const float* W_w    = (const float*)d_in[3];
  const float* b_w    = (const float*)d_in[4];
  const float* W_c    = (const float*)d_in[5];
  const float* b_c    = (const float*)d_in[6];
  const float* W_d    = (const float*)d_in[7];
  const float* b_d    = (const float*)d_in[8];
  const float* W_attn = (const float*)d_in[9];
  const float* b_attn = (const float*)d_in[10];
  const float* W_1    = (const float*)d_in[11];
  const float* b_1    = (const float*)d_in[12];
  const float* W_2    = (const float*)d_in[13];
  const float* b_2    = (const float*)d_in[14];
  const float* W_3    = (const float*)d_in[15];
  const float* b_3    = (const float*)d_in[16];
  float* outp = (float*)d_out;

  u16* WT = (u16*)d_ws;             // 8 * 65536 bf16 (1 MiB)
  u16* R1 = WT + 8 * 65536;         // 64 MiB: att -> x1_blk
  u16* R2 = R1 + 33554432;          // 64 MiB: xd

  // slots: 0:h 1:w 2:c 3:attn 4:W1 5:Wd 6:W2 7:W3(+I)
  k_pack_all<<<2048, 64, 0, stream>>>(W_h, W_w, W_c, W_attn, W_1, W_d, W_2, W_3, WT);

  k_att <<<1024, 512, 0, stream>>>(x, WT + 3 * 65536, b_attn, R1);
  k_hw  <<<512, 512, 0, stream>>>(x, WT + 0 * 65536, WT + 1 * 65536, (char*)outp);
  k_comb<<<1024, 512, 0, stream>>>(x, (const char*)outp, R1, b_h, b_w, b_c,
                                   WT + 2 * 65536, WT + 4 * 65536, b_1, R1);
  k_d   <<<1024, 512, 0, stream>>>(R1, WT + 5 * 65536, b_d, R2);
  k_fin <<<1024, 512, 0, stream>>>(R1, R2, WT + 6 * 65536, WT + 7 * 65536, b_2, b_3, outp);
}